// Round 1
// baseline (188.398 us; speedup 1.0000x reference)
//
#include <hip/hip_runtime.h>
#include <hip/hip_bf16.h>

// CausalSelfAttention  B=1, T=4096, C=768, H=12, hd=64
// Round 15: flash kernel is latency-bound (MfmaUtil 15%, VALUBusy 33%,
//   HBM 4%, ~2500 cyc/iter vs ~200 compute). Two changes:
//   (a) distance-2 K/V prefetch: triple-buffered LDS (48KB, still 3 blk/CU)
//       with counted `s_waitcnt vmcnt(4)` + raw s_barrier instead of the
//       __syncthreads() vmcnt(0) drain -> 2-iter-body latency hiding.
//   (b) head-local XCD block mapping: xcd=bid&7 serves 3 half-heads
//       (~2 heads = 2.1MB K+V < 4MB L2) instead of all 12 heads (12.6MB
//       thrash -> L3 latency). Balance comparable to old monotone LPT.
//   GEMMs unchanged from R14.

#define T_SEQ 4096
#define C_DIM 768
#define C3    2304
#define NH    12
#define HD    64

typedef __attribute__((ext_vector_type(8))) short bf16x8;
typedef __attribute__((ext_vector_type(4))) short bf16x4;
typedef __attribute__((ext_vector_type(4))) float f32x4;

__device__ inline unsigned short f2bf(float f) {
  union { float f; unsigned u; } v; v.f = f;
  unsigned r = v.u + 0x7fff + ((v.u >> 16) & 1);  // RTNE
  return (unsigned short)(r >> 16);
}
__device__ inline unsigned short f2bf_trunc(float f) {
  union { float f; unsigned u; } v; v.f = f;
  return (unsigned short)(v.u >> 16);  // truncate: fine for P >= 0
}

__device__ inline void gl2lds16(const void* g, void* l) {
  __builtin_amdgcn_global_load_lds(
      (const __attribute__((address_space(1))) unsigned int*)g,
      (__attribute__((address_space(3))) unsigned int*)l, 16, 0, 0);
}

#if __has_builtin(__builtin_amdgcn_exp2f)
#define EXP2F(x) __builtin_amdgcn_exp2f(x)
#else
#define EXP2F(x) exp2f(x)
#endif

// ---------------------------------------------------------------------------
// fused prep: conv x->bf16 | transpose w_qkv | transpose w_proj
// ---------------------------------------------------------------------------
#define NB_CONV  (T_SEQ * C_DIM / 2048)          // 1536
#define NB_TQKV  ((C3 / 32) * (C_DIM / 32))      // 1728
#define NB_TPROJ ((C_DIM / 32) * (C_DIM / 32))   // 576

__global__ __launch_bounds__(256) void prep_fused(
    const float* __restrict__ x, const float* __restrict__ w_qkv,
    const float* __restrict__ w_proj, unsigned short* __restrict__ xb,
    unsigned short* __restrict__ wqkvT, unsigned short* __restrict__ wprojT) {
  __shared__ float t[32][33];
  const int b = blockIdx.x;
  const int tid = threadIdx.x;

  if (b < NB_CONV) {
    int i = (b * 256 + tid) * 8;
    float4 v0 = *(const float4*)(x + i);
    float4 v1 = *(const float4*)(x + i + 4);
    unsigned short o[8] = {f2bf(v0.x), f2bf(v0.y), f2bf(v0.z), f2bf(v0.w),
                           f2bf(v1.x), f2bf(v1.y), f2bf(v1.z), f2bf(v1.w)};
    *(uint4*)(xb + i) = *(uint4*)o;
    return;
  }
  const float* in;
  unsigned short* outT;
  int R, Cc, bi;
  if (b < NB_CONV + NB_TQKV) {
    in = w_qkv; outT = wqkvT; R = C_DIM; Cc = C3; bi = b - NB_CONV;
  } else {
    in = w_proj; outT = wprojT; R = C_DIM; Cc = C_DIM; bi = b - NB_CONV - NB_TQKV;
  }
  const int tx = tid & 31, ty = tid >> 5;
  const int c0 = (bi % (Cc / 32)) * 32, r0 = (bi / (Cc / 32)) * 32;
#pragma unroll
  for (int i = 0; i < 4; ++i) {
    int r = ty + i * 8;
    t[r][tx] = in[(size_t)(r0 + r) * Cc + c0 + tx];
  }
  __syncthreads();
#pragma unroll
  for (int i = 0; i < 4; ++i) {
    int c = ty + i * 8;
    outT[(size_t)(c0 + c) * R + r0 + tx] = f2bf(t[tx][c]);
  }
}

// ---------------------------------------------------------------------------
// gemm1: qkv = xb @ wqkvT^T + b_qkv; V blocks write k-permuted vTp directly.
// BK=64, XOR-swizzled LDS (chunk c of row r at slot c^(r&7)); 12 k-iters.
// ---------------------------------------------------------------------------
__global__ __launch_bounds__(256) void gemm_qkv(
    const unsigned short* __restrict__ A, const unsigned short* __restrict__ Bt,
    const float* __restrict__ bias, unsigned short* __restrict__ Cq,
    unsigned short* __restrict__ vTp, int M, int N, int K) {
  __shared__ unsigned short As[128 * 64];
  __shared__ unsigned short Bs[128 * 64];
  const int tid = threadIdx.x;
  const int wave = tid >> 6, lane = tid & 63;
  const int lo = lane & 15, g8 = lane >> 4;
  const int lo7 = lo & 7;
  const int wm = wave >> 1, wn = wave & 1;
  const int bm = blockIdx.y * 128, bn = blockIdx.x * 128;
  const int drow8 = lane >> 3;               // 0..7
  const int dslot = (lane & 7) * 8;
  const int dsrc = ((lane & 7) ^ drow8) * 8; // swizzled source chunk

  f32x4 acc[4][4];
#pragma unroll
  for (int mt = 0; mt < 4; ++mt)
#pragma unroll
    for (int nt = 0; nt < 4; ++nt) acc[mt][nt] = (f32x4){0.f, 0.f, 0.f, 0.f};

  const unsigned short* Abase = A + (size_t)bm * K;
  const unsigned short* Bbase = Bt + (size_t)bn * K;

  for (int k0 = 0; k0 < K; k0 += 64) {
    __syncthreads();
#pragma unroll
    for (int p = 0; p < 4; ++p) {
      const int r = p * 32 + wave * 8 + drow8;
      gl2lds16(Abase + (size_t)r * K + k0 + dsrc, As + r * 64 + dslot);
      gl2lds16(Bbase + (size_t)r * K + k0 + dsrc, Bs + r * 64 + dslot);
    }
    __syncthreads();

#pragma unroll
    for (int kk = 0; kk < 2; ++kk) {
      bf16x8 a[4], b[4];
#pragma unroll
      for (int mt = 0; mt < 4; ++mt)
        a[mt] = *(const bf16x8*)(
            As + (wm * 64 + mt * 16 + lo) * 64 + (((kk * 4 + g8) ^ lo7) * 8));
#pragma unroll
      for (int nt = 0; nt < 4; ++nt)
        b[nt] = *(const bf16x8*)(
            Bs + (wn * 64 + nt * 16 + lo) * 64 + (((kk * 4 + g8) ^ lo7) * 8));
#pragma unroll
      for (int mt = 0; mt < 4; ++mt)
#pragma unroll
        for (int nt = 0; nt < 4; ++nt)
          acc[mt][nt] = __builtin_amdgcn_mfma_f32_16x16x32_bf16(a[mt], b[nt], acc[mt][nt], 0, 0, 0);
    }
  }

  if (bn < 2 * C_DIM) {
#pragma unroll
    for (int nt = 0; nt < 4; ++nt) {
      const int n = bn + wn * 64 + nt * 16 + lo;
      const float bv = bias[n];
#pragma unroll
      for (int mt = 0; mt < 4; ++mt)
#pragma unroll
        for (int r = 0; r < 4; ++r) {
          const int m = bm + wm * 64 + mt * 16 + g8 * 4 + r;
          Cq[(size_t)m * C3 + n] = f2bf(acc[mt][nt][r] + bv);
        }
    }
  } else {
#pragma unroll
    for (int nt = 0; nt < 4; ++nt) {
      const int n = bn + wn * 64 + nt * 16 + lo;
      const float bv = bias[n];
      unsigned short* row = vTp + (size_t)(n - 2 * C_DIM) * T_SEQ;
#pragma unroll
      for (int mt = 0; mt < 4; ++mt) {
        const int mbase = (bm + wm * 64 + mt * 16 + g8 * 4) & ~31;
        bf16x4 o4;
#pragma unroll
        for (int r = 0; r < 4; ++r) o4[r] = (short)f2bf(acc[mt][nt][r] + bv);
        *(bf16x4*)(row + mbase + 8 * g8 + 4 * (mt & 1)) = o4;
      }
    }
  }
}

// ---------------------------------------------------------------------------
// gemm2: bf16 MFMA GEMM, B^T input, fp32 out. BK=64 swizzled (as gemm1).
// ---------------------------------------------------------------------------
__global__ __launch_bounds__(256) void gemm_bt_mfma(
    const unsigned short* __restrict__ A, const unsigned short* __restrict__ Bt,
    const float* __restrict__ bias, float* __restrict__ C,
    int M, int N, int K) {
  __shared__ unsigned short As[128 * 64];
  __shared__ unsigned short Bs[128 * 64];
  const int tid = threadIdx.x;
  const int wave = tid >> 6, lane = tid & 63;
  const int lo = lane & 15, g8 = lane >> 4;
  const int lo7 = lo & 7;
  const int wm = wave >> 1, wn = wave & 1;
  const int bm = blockIdx.y * 128, bn = blockIdx.x * 128;
  const int drow8 = lane >> 3;
  const int dslot = (lane & 7) * 8;
  const int dsrc = ((lane & 7) ^ drow8) * 8;

  f32x4 acc[4][4];
#pragma unroll
  for (int mt = 0; mt < 4; ++mt)
#pragma unroll
    for (int nt = 0; nt < 4; ++nt) acc[mt][nt] = (f32x4){0.f, 0.f, 0.f, 0.f};

  const unsigned short* Abase = A + (size_t)bm * K;
  const unsigned short* Bbase = Bt + (size_t)bn * K;

  for (int k0 = 0; k0 < K; k0 += 64) {
    __syncthreads();
#pragma unroll
    for (int p = 0; p < 4; ++p) {
      const int r = p * 32 + wave * 8 + drow8;
      gl2lds16(Abase + (size_t)r * K + k0 + dsrc, As + r * 64 + dslot);
      gl2lds16(Bbase + (size_t)r * K + k0 + dsrc, Bs + r * 64 + dslot);
    }
    __syncthreads();

#pragma unroll
    for (int kk = 0; kk < 2; ++kk) {
      bf16x8 a[4], b[4];
#pragma unroll
      for (int mt = 0; mt < 4; ++mt)
        a[mt] = *(const bf16x8*)(
            As + (wm * 64 + mt * 16 + lo) * 64 + (((kk * 4 + g8) ^ lo7) * 8));
#pragma unroll
      for (int nt = 0; nt < 4; ++nt)
        b[nt] = *(const bf16x8*)(
            Bs + (wn * 64 + nt * 16 + lo) * 64 + (((kk * 4 + g8) ^ lo7) * 8));
#pragma unroll
      for (int mt = 0; mt < 4; ++mt)
#pragma unroll
        for (int nt = 0; nt < 4; ++nt)
          acc[mt][nt] = __builtin_amdgcn_mfma_f32_16x16x32_bf16(a[mt], b[nt], acc[mt][nt], 0, 0, 0);
    }
  }

#pragma unroll
  for (int nt = 0; nt < 4; ++nt) {
    const int n = bn + wn * 64 + nt * 16 + lo;
    const float bv = bias[n];
#pragma unroll
    for (int mt = 0; mt < 4; ++mt)
#pragma unroll
      for (int r = 0; r < 4; ++r) {
        const int m = bm + wm * 64 + mt * 16 + g8 * 4 + r;
        C[(size_t)m * N + n] = acc[mt][nt][r] + bv;
      }
  }
}

// ---------------------------------------------------------------------------
// flash v13: R11/R14 math unchanged. New schedule:
//  - triple-buffered K/V LDS (48KB), prefetch distance 2
//  - counted s_waitcnt vmcnt(4) + raw s_barrier per iter (never full drain
//    in steady state) -> DMA latency hidden under ~2 iter bodies
//  - head-local XCD mapping: xcd=bid&7 handles 3 half-heads (~2 heads of
//    K/V = 2.1MB, fits per-XCD 4MB L2). qt stagger keeps per-CU balance.
// ---------------------------------------------------------------------------
__global__ __launch_bounds__(256) void flash_attn_mfma13(
    const unsigned short* __restrict__ qkv,   // [T][2304] bf16 (Q,K valid)
    const unsigned short* __restrict__ vTp,   // [768][T] bf16, k-permuted
    unsigned short* __restrict__ out) {       // [T][768] bf16
  __shared__ unsigned short Ks[3][64 * 64];
  __shared__ unsigned short Vs[3][64 * 64];

  // --- head-local XCD mapping (assumes XCD = blockIdx.x & 7 round-robin) ---
  const int bid = blockIdx.x;
  const int xcd = bid & 7;
  const int j = bid >> 3;              // 0..95 within XCD
  const int slot = j >> 5;             // 0..2 : which half-head on this XCD
  const int cc = j & 31;               // 0..31
  const int Hh = 3 * xcd + slot;       // half-head index 0..23
  const int h = Hh >> 1;               // head 0..11
  const int par = Hh & 1;              // qt parity for this half-head
  // stagger qi across slots so one CU's 3 blocks don't all have large qt
  const int qi = (slot == 0) ? cc : (slot == 1) ? (31 - cc) : (cc ^ 16);
  const int qt = 2 * qi + par;         // 0..63, bijective over (h,qt)
  const int q0 = qt * 64;

  const int tid = threadIdx.x;
  const int w = tid >> 6;
  const int lane = tid & 63;
  const int lo = lane & 15;
  const int g = lane >> 4;
  const int lo7 = lo & 7;
  const float qscale = 0.125f * 1.44269504f;  // 1/sqrt(64) * log2(e)

  const unsigned short* Kg = qkv + C_DIM + h * HD;           // row stride C3
  const unsigned short* Vg = vTp + (size_t)(h * HD) * T_SEQ; // row stride T_SEQ

  const int drow = tid >> 3;                    // 0..31
  const int dslot = (tid & 7) * 8;
  const int dsrc = ((tid & 7) ^ (drow & 7)) * 8;

  // Q B-frags direct from global (one-time) -- issued BEFORE the DMAs so
  // in-order vmcnt retirement means our counted waits also cover them.
  bf16x8 qb[2];
#pragma unroll
  for (int dh = 0; dh < 2; ++dh)
    qb[dh] = *(const bf16x8*)(
        qkv + (size_t)(q0 + w * 16 + lo) * C3 + h * HD + dh * 32 + g * 8);

  // prologue: DMA tile 0 (and tile 1 if present) -- distance-2 pipeline
#pragma unroll
  for (int p2 = 0; p2 < 2; ++p2) {
    const int r = p2 * 32 + drow;
    gl2lds16(Kg + (size_t)r * C3 + dsrc, Ks[0] + r * 64 + dslot);
    gl2lds16(Vg + (size_t)r * T_SEQ + dsrc, Vs[0] + r * 64 + dslot);
  }
  if (qt >= 1) {
#pragma unroll
    for (int p2 = 0; p2 < 2; ++p2) {
      const int r = p2 * 32 + drow;
      gl2lds16(Kg + (size_t)(64 + r) * C3 + dsrc, Ks[1] + r * 64 + dslot);
      gl2lds16(Vg + (size_t)r * T_SEQ + 64 + dsrc, Vs[1] + r * 64 + dslot);
    }
    // tile 0 (and qb) done; tile 1's 4 DMAs may stay in flight
    asm volatile("s_waitcnt vmcnt(4)" ::: "memory");
  } else {
    asm volatile("s_waitcnt vmcnt(0)" ::: "memory");
  }
  __builtin_amdgcn_s_barrier();

  float l_i = 0.f;
  f32x4 o_acc[4];
#pragma unroll
  for (int dt = 0; dt < 4; ++dt) o_acc[dt] = (f32x4){0.f, 0.f, 0.f, 0.f};

  int ic = 0;  // buffer being consumed (t % 3)
  int iw = 2;  // buffer being filled   ((t+2) % 3)
  for (int t = 0; t <= qt; ++t) {
    if (t + 2 <= qt) {
      const int k0n = (t + 2) * 64;
      unsigned short* Kd = Ks[iw];
      unsigned short* Vd = Vs[iw];
#pragma unroll
      for (int p2 = 0; p2 < 2; ++p2) {
        const int r = p2 * 32 + drow;
        gl2lds16(Kg + (size_t)(k0n + r) * C3 + dsrc, Kd + r * 64 + dslot);
        gl2lds16(Vg + (size_t)r * T_SEQ + k0n + dsrc, Vd + r * 64 + dslot);
      }
    }
    const unsigned short* Kc = Ks[ic];
    const unsigned short* Vc = Vs[ic];

    // St = K @ Q^T
    f32x4 st[4];
#pragma unroll
    for (int mt = 0; mt < 4; ++mt) st[mt] = (f32x4){0.f, 0.f, 0.f, 0.f};
#pragma unroll
    for (int mt = 0; mt < 4; ++mt)
#pragma unroll
      for (int dh = 0; dh < 2; ++dh) {
        bf16x8 a = *(const bf16x8*)(
            Kc + (mt * 16 + lo) * 64 + (((dh * 4 + g) ^ lo7) * 8));
        st[mt] = __builtin_amdgcn_mfma_f32_16x16x32_bf16(a, qb[dh], st[mt], 0, 0, 0);
      }

    // causal mask (last tile only) -> exact zeros after exp2
    if (t == qt) {
      const int qloc = w * 16 + lo;
#pragma unroll
      for (int mt = 0; mt < 4; ++mt)
#pragma unroll
        for (int r = 0; r < 4; ++r)
          if (mt * 16 + g * 4 + r > qloc) st[mt][r] = -1e30f;
    }

    // no-max softmax: e = exp2(s * qscale)  (R11 codegen — per-element pack)
    float lsum = 0.f;
    bf16x8 pt[2];
#pragma unroll
    for (int kh = 0; kh < 2; ++kh) {
#pragma unroll
      for (int jj = 0; jj < 4; ++jj) {
        float e0 = EXP2F(st[kh * 2][jj] * qscale);
        float e1 = EXP2F(st[kh * 2 + 1][jj] * qscale);
        lsum += e0 + e1;
        pt[kh][jj] = (short)f2bf_trunc(e0);
        pt[kh][4 + jj] = (short)f2bf_trunc(e1);
      }
    }
    l_i += lsum;  // cross-lane reduce deferred to epilogue

    // O^T += V^T @ P^T
#pragma unroll
    for (int dt = 0; dt < 4; ++dt)
#pragma unroll
      for (int kh = 0; kh < 2; ++kh) {
        bf16x8 av = *(const bf16x8*)(
            Vc + (dt * 16 + lo) * 64 + (((kh * 4 + g) ^ lo7) * 8));
        o_acc[dt] = __builtin_amdgcn_mfma_f32_16x16x32_bf16(av, pt[kh], o_acc[dt], 0, 0, 0);
      }

    // counted wait: tile t+1 must be complete before next iter reads it.
    // The only VMEM ops newer than tile t+1's 4 DMAs are tile t+2's 4
    // (if issued this iter) -> vmcnt(4); in the tail, full drain.
    if (t + 2 <= qt)
      asm volatile("s_waitcnt vmcnt(4)" ::: "memory");
    else
      asm volatile("s_waitcnt vmcnt(0)" ::: "memory");
    __builtin_amdgcn_s_barrier();

    ic = (ic == 2) ? 0 : ic + 1;
    iw = (iw == 2) ? 0 : iw + 1;
  }

  // epilogue (all DMAs drained by last iter's vmcnt(0) + barrier)
  l_i += __shfl_xor(l_i, 16);
  l_i += __shfl_xor(l_i, 32);
  const float inv = 1.0f / l_i;
  unsigned short* Es = Ks[0];
#pragma unroll
  for (int dt = 0; dt < 4; ++dt) {
    const int chunk = (dt * 2 + (g >> 1)) ^ lo7;
#pragma unroll
    for (int r = 0; r < 4; ++r)
      Es[(w * 16 + lo) * 64 + chunk * 8 + (g & 1) * 4 + r] =
          f2bf(o_acc[dt][r] * inv);
  }
#pragma unroll
  for (int i = 0; i < 2; ++i) {
    const int row = w * 16 + i * 8 + (lane >> 3);
    bf16x8 val = *(const bf16x8*)(Es + row * 64 + (((lane & 7) ^ (row & 7)) * 8));
    *(bf16x8*)(out + (size_t)(q0 + row) * C_DIM + h * HD + (lane & 7) * 8) = val;
  }
}

// ---------------------------------------------------------------------------
extern "C" void kernel_launch(void* const* d_in, const int* in_sizes, int n_in,
                              void* d_out, int out_size, void* d_ws, size_t ws_size,
                              hipStream_t stream) {
  const float* x      = (const float*)d_in[0];
  const float* w_qkv  = (const float*)d_in[1];
  const float* b_qkv  = (const float*)d_in[2];
  const float* w_proj = (const float*)d_in[3];
  const float* b_proj = (const float*)d_in[4];
  float* out = (float*)d_out;

  unsigned short* xb     = (unsigned short*)d_ws;               // [4096,768]
  unsigned short* wqkvT  = xb + (size_t)T_SEQ * C_DIM;          // [2304,768]
  unsigned short* wprojT = wqkvT + (size_t)C3 * C_DIM;          // [768,768]
  unsigned short* qkv    = wprojT + (size_t)C_DIM * C_DIM;      // [4096,2304]
  unsigned short* vTp    = qkv + (size_t)T_SEQ * C3;            // [768,4096]
  unsigned short* attnb  = vTp + (size_t)C_DIM * T_SEQ;         // [4096,768]

  prep_fused<<<NB_CONV + NB_TQKV + NB_TPROJ, 256, 0, stream>>>(
      x, w_qkv, w_proj, xb, wqkvT, wprojT);

  gemm_qkv<<<dim3(C3 / 128, T_SEQ / 128), 256, 0, stream>>>(
      xb, wqkvT, b_qkv, qkv, vTp, T_SEQ, C3, C_DIM);

  flash_attn_mfma13<<<T_SEQ / 64 * NH, 256, 0, stream>>>(qkv, vTp, attnb);

  gemm_bt_mfma<<<dim3(C_DIM / 128, T_SEQ / 128), 256, 0, stream>>>(
      attnb, wprojT, b_proj, out, T_SEQ, C_DIM, C_DIM);
}

// Round 2
// 180.637 us; speedup vs baseline: 1.0430x; 1.0430x over previous
//
#include <hip/hip_runtime.h>
#include <hip/hip_bf16.h>

// CausalSelfAttention  B=1, T=4096, C=768, H=12, hd=64
// Round 16: flash is serial-depth bound (makespan = 64 barrier-synced
//   iterations x ~2470cyc chain; R15's prefetch/XCD fixes changed FETCH but
//   not time). No-max softmax => split-k partials combine ADDITIVELY.
//   New: pair (i,63-i), split the 65 k-tile tasks into two equal sub-blocks
//   (33/32 iters) -> 768 EQUAL blocks, depth 64->33. Blocks write fp32
//   (O,l) partials; tiny combine kernel normalizes -> attnb.
//   Iteration body / swizzle / counted-vmcnt pipeline identical to R15.

#define T_SEQ 4096
#define C_DIM 768
#define C3    2304
#define NH    12
#define HD    64

typedef __attribute__((ext_vector_type(8))) short bf16x8;
typedef __attribute__((ext_vector_type(4))) short bf16x4;
typedef __attribute__((ext_vector_type(4))) float f32x4;

__device__ inline unsigned short f2bf(float f) {
  union { float f; unsigned u; } v; v.f = f;
  unsigned r = v.u + 0x7fff + ((v.u >> 16) & 1);  // RTNE
  return (unsigned short)(r >> 16);
}
__device__ inline unsigned short f2bf_trunc(float f) {
  union { float f; unsigned u; } v; v.f = f;
  return (unsigned short)(v.u >> 16);  // truncate: fine for P >= 0
}

__device__ inline void gl2lds16(const void* g, void* l) {
  __builtin_amdgcn_global_load_lds(
      (const __attribute__((address_space(1))) unsigned int*)g,
      (__attribute__((address_space(3))) unsigned int*)l, 16, 0, 0);
}

#if __has_builtin(__builtin_amdgcn_exp2f)
#define EXP2F(x) __builtin_amdgcn_exp2f(x)
#else
#define EXP2F(x) exp2f(x)
#endif

// ---------------------------------------------------------------------------
// fused prep: conv x->bf16 | transpose w_qkv | transpose w_proj
// ---------------------------------------------------------------------------
#define NB_CONV  (T_SEQ * C_DIM / 2048)          // 1536
#define NB_TQKV  ((C3 / 32) * (C_DIM / 32))      // 1728
#define NB_TPROJ ((C_DIM / 32) * (C_DIM / 32))   // 576

__global__ __launch_bounds__(256) void prep_fused(
    const float* __restrict__ x, const float* __restrict__ w_qkv,
    const float* __restrict__ w_proj, unsigned short* __restrict__ xb,
    unsigned short* __restrict__ wqkvT, unsigned short* __restrict__ wprojT) {
  __shared__ float t[32][33];
  const int b = blockIdx.x;
  const int tid = threadIdx.x;

  if (b < NB_CONV) {
    int i = (b * 256 + tid) * 8;
    float4 v0 = *(const float4*)(x + i);
    float4 v1 = *(const float4*)(x + i + 4);
    unsigned short o[8] = {f2bf(v0.x), f2bf(v0.y), f2bf(v0.z), f2bf(v0.w),
                           f2bf(v1.x), f2bf(v1.y), f2bf(v1.z), f2bf(v1.w)};
    *(uint4*)(xb + i) = *(uint4*)o;
    return;
  }
  const float* in;
  unsigned short* outT;
  int R, Cc, bi;
  if (b < NB_CONV + NB_TQKV) {
    in = w_qkv; outT = wqkvT; R = C_DIM; Cc = C3; bi = b - NB_CONV;
  } else {
    in = w_proj; outT = wprojT; R = C_DIM; Cc = C_DIM; bi = b - NB_CONV - NB_TQKV;
  }
  const int tx = tid & 31, ty = tid >> 5;
  const int c0 = (bi % (Cc / 32)) * 32, r0 = (bi / (Cc / 32)) * 32;
#pragma unroll
  for (int i = 0; i < 4; ++i) {
    int r = ty + i * 8;
    t[r][tx] = in[(size_t)(r0 + r) * Cc + c0 + tx];
  }
  __syncthreads();
#pragma unroll
  for (int i = 0; i < 4; ++i) {
    int c = ty + i * 8;
    outT[(size_t)(c0 + c) * R + r0 + tx] = f2bf(t[tx][c]);
  }
}

// ---------------------------------------------------------------------------
// gemm1: qkv = xb @ wqkvT^T + b_qkv; V blocks write k-permuted vTp directly.
// ---------------------------------------------------------------------------
__global__ __launch_bounds__(256) void gemm_qkv(
    const unsigned short* __restrict__ A, const unsigned short* __restrict__ Bt,
    const float* __restrict__ bias, unsigned short* __restrict__ Cq,
    unsigned short* __restrict__ vTp, int M, int N, int K) {
  __shared__ unsigned short As[128 * 64];
  __shared__ unsigned short Bs[128 * 64];
  const int tid = threadIdx.x;
  const int wave = tid >> 6, lane = tid & 63;
  const int lo = lane & 15, g8 = lane >> 4;
  const int lo7 = lo & 7;
  const int wm = wave >> 1, wn = wave & 1;
  const int bm = blockIdx.y * 128, bn = blockIdx.x * 128;
  const int drow8 = lane >> 3;               // 0..7
  const int dslot = (lane & 7) * 8;
  const int dsrc = ((lane & 7) ^ drow8) * 8; // swizzled source chunk

  f32x4 acc[4][4];
#pragma unroll
  for (int mt = 0; mt < 4; ++mt)
#pragma unroll
    for (int nt = 0; nt < 4; ++nt) acc[mt][nt] = (f32x4){0.f, 0.f, 0.f, 0.f};

  const unsigned short* Abase = A + (size_t)bm * K;
  const unsigned short* Bbase = Bt + (size_t)bn * K;

  for (int k0 = 0; k0 < K; k0 += 64) {
    __syncthreads();
#pragma unroll
    for (int p = 0; p < 4; ++p) {
      const int r = p * 32 + wave * 8 + drow8;
      gl2lds16(Abase + (size_t)r * K + k0 + dsrc, As + r * 64 + dslot);
      gl2lds16(Bbase + (size_t)r * K + k0 + dsrc, Bs + r * 64 + dslot);
    }
    __syncthreads();

#pragma unroll
    for (int kk = 0; kk < 2; ++kk) {
      bf16x8 a[4], b[4];
#pragma unroll
      for (int mt = 0; mt < 4; ++mt)
        a[mt] = *(const bf16x8*)(
            As + (wm * 64 + mt * 16 + lo) * 64 + (((kk * 4 + g8) ^ lo7) * 8));
#pragma unroll
      for (int nt = 0; nt < 4; ++nt)
        b[nt] = *(const bf16x8*)(
            Bs + (wn * 64 + nt * 16 + lo) * 64 + (((kk * 4 + g8) ^ lo7) * 8));
#pragma unroll
      for (int mt = 0; mt < 4; ++mt)
#pragma unroll
        for (int nt = 0; nt < 4; ++nt)
          acc[mt][nt] = __builtin_amdgcn_mfma_f32_16x16x32_bf16(a[mt], b[nt], acc[mt][nt], 0, 0, 0);
    }
  }

  if (bn < 2 * C_DIM) {
#pragma unroll
    for (int nt = 0; nt < 4; ++nt) {
      const int n = bn + wn * 64 + nt * 16 + lo;
      const float bv = bias[n];
#pragma unroll
      for (int mt = 0; mt < 4; ++mt)
#pragma unroll
        for (int r = 0; r < 4; ++r) {
          const int m = bm + wm * 64 + mt * 16 + g8 * 4 + r;
          Cq[(size_t)m * C3 + n] = f2bf(acc[mt][nt][r] + bv);
        }
    }
  } else {
#pragma unroll
    for (int nt = 0; nt < 4; ++nt) {
      const int n = bn + wn * 64 + nt * 16 + lo;
      const float bv = bias[n];
      unsigned short* row = vTp + (size_t)(n - 2 * C_DIM) * T_SEQ;
#pragma unroll
      for (int mt = 0; mt < 4; ++mt) {
        const int mbase = (bm + wm * 64 + mt * 16 + g8 * 4) & ~31;
        bf16x4 o4;
#pragma unroll
        for (int r = 0; r < 4; ++r) o4[r] = (short)f2bf(acc[mt][nt][r] + bv);
        *(bf16x4*)(row + mbase + 8 * g8 + 4 * (mt & 1)) = o4;
      }
    }
  }
}

// ---------------------------------------------------------------------------
// gemm2: bf16 MFMA GEMM, B^T input, fp32 out.
// ---------------------------------------------------------------------------
__global__ __launch_bounds__(256) void gemm_bt_mfma(
    const unsigned short* __restrict__ A, const unsigned short* __restrict__ Bt,
    const float* __restrict__ bias, float* __restrict__ C,
    int M, int N, int K) {
  __shared__ unsigned short As[128 * 64];
  __shared__ unsigned short Bs[128 * 64];
  const int tid = threadIdx.x;
  const int wave = tid >> 6, lane = tid & 63;
  const int lo = lane & 15, g8 = lane >> 4;
  const int lo7 = lo & 7;
  const int wm = wave >> 1, wn = wave & 1;
  const int bm = blockIdx.y * 128, bn = blockIdx.x * 128;
  const int drow8 = lane >> 3;
  const int dslot = (lane & 7) * 8;
  const int dsrc = ((lane & 7) ^ drow8) * 8;

  f32x4 acc[4][4];
#pragma unroll
  for (int mt = 0; mt < 4; ++mt)
#pragma unroll
    for (int nt = 0; nt < 4; ++nt) acc[mt][nt] = (f32x4){0.f, 0.f, 0.f, 0.f};

  const unsigned short* Abase = A + (size_t)bm * K;
  const unsigned short* Bbase = Bt + (size_t)bn * K;

  for (int k0 = 0; k0 < K; k0 += 64) {
    __syncthreads();
#pragma unroll
    for (int p = 0; p < 4; ++p) {
      const int r = p * 32 + wave * 8 + drow8;
      gl2lds16(Abase + (size_t)r * K + k0 + dsrc, As + r * 64 + dslot);
      gl2lds16(Bbase + (size_t)r * K + k0 + dsrc, Bs + r * 64 + dslot);
    }
    __syncthreads();

#pragma unroll
    for (int kk = 0; kk < 2; ++kk) {
      bf16x8 a[4], b[4];
#pragma unroll
      for (int mt = 0; mt < 4; ++mt)
        a[mt] = *(const bf16x8*)(
            As + (wm * 64 + mt * 16 + lo) * 64 + (((kk * 4 + g8) ^ lo7) * 8));
#pragma unroll
      for (int nt = 0; nt < 4; ++nt)
        b[nt] = *(const bf16x8*)(
            Bs + (wn * 64 + nt * 16 + lo) * 64 + (((kk * 4 + g8) ^ lo7) * 8));
#pragma unroll
      for (int mt = 0; mt < 4; ++mt)
#pragma unroll
        for (int nt = 0; nt < 4; ++nt)
          acc[mt][nt] = __builtin_amdgcn_mfma_f32_16x16x32_bf16(a[mt], b[nt], acc[mt][nt], 0, 0, 0);
    }
  }

#pragma unroll
  for (int nt = 0; nt < 4; ++nt) {
    const int n = bn + wn * 64 + nt * 16 + lo;
    const float bv = bias[n];
#pragma unroll
    for (int mt = 0; mt < 4; ++mt)
#pragma unroll
      for (int r = 0; r < 4; ++r) {
        const int m = bm + wm * 64 + mt * 16 + g8 * 4 + r;
        C[(size_t)m * N + n] = acc[mt][nt][r] + bv;
      }
  }
}

// ---------------------------------------------------------------------------
// flash v14: equal-depth split-k. Pair (i, j=63-i) has 65 k-tile tasks
// (all of q-tile j: k 0..j, then all of q-tile i: k 0..i). s=0 takes the
// first 33 tasks (always within q-tile j), s=1 the remaining 32 (tail of
// j, then all of i). Unnormalized fp32 (O,l) partials; additive combine.
//   slot0 <- s=0 J-flush (qt>=32) or s=1 I-flush (qt<=31)
//   slot1 <- s=1 J-flush (qt>=33 only)
// ---------------------------------------------------------------------------
#define PO_SLOT ((size_t)NH * 64 * 4096)   // floats per slot
#define PL_SLOT ((size_t)NH * 64 * 64)

__global__ __launch_bounds__(256) void flash_attn_split14(
    const unsigned short* __restrict__ qkv,   // [T][2304] bf16 (Q,K valid)
    const unsigned short* __restrict__ vTp,   // [768][T] bf16, k-permuted
    float* __restrict__ Po, float* __restrict__ Pl) {
  __shared__ unsigned short Ks[3][64 * 64];
  __shared__ unsigned short Vs[3][64 * 64];

  // head-local XCD mapping: each XCD serves 3 (h,s) strips (~1.5 heads of K/V)
  const int bid = blockIdx.x;
  const int xcd = bid & 7;
  const int j2 = bid >> 3;             // 0..95
  const int Hh = xcd * 3 + (j2 >> 5);  // 0..23
  const int h = Hh >> 1;
  const int s = Hh & 1;
  const int i = j2 & 31;               // pair index
  const int j = 63 - i;                // partner q-tile
  const int nJ = s ? (31 - i) : 33;    // J-segment length (k-tiles of q-tile j)
  const int kJ0 = s ? 33 : 0;          // first k-tile of J segment
  const int nI = s ? (i + 1) : 0;      // I-segment length (k-tiles of q-tile i)
  const int T = nJ + nI;               // 32 or 33

  const int tid = threadIdx.x;
  const int w = tid >> 6;
  const int lane = tid & 63;
  const int lo = lane & 15;
  const int g = lane >> 4;
  const int lo7 = lo & 7;
  const float qscale = 0.125f * 1.44269504f;  // 1/sqrt(64) * log2(e)

  const unsigned short* Kg = qkv + C_DIM + h * HD;           // row stride C3
  const unsigned short* Vg = vTp + (size_t)(h * HD) * T_SEQ; // row stride T_SEQ

  const int drow = tid >> 3;                    // 0..31
  const int dslot = (tid & 7) * 8;
  const int dsrc = ((tid & 7) ^ (drow & 7)) * 8;

  // Q B-frags for both segments, issued BEFORE the DMAs (in-order vmcnt
  // retirement => the prologue's counted wait also covers them).
  bf16x8 qbJ[2], qbI[2];
#pragma unroll
  for (int dh = 0; dh < 2; ++dh)
    qbJ[dh] = *(const bf16x8*)(
        qkv + (size_t)(j * 64 + w * 16 + lo) * C3 + h * HD + dh * 32 + g * 8);
#pragma unroll
  for (int dh = 0; dh < 2; ++dh)
    qbI[dh] = *(const bf16x8*)(
        qkv + (size_t)(i * 64 + w * 16 + lo) * C3 + h * HD + dh * 32 + g * 8);

  auto KT = [&](int t) { return t < nJ ? kJ0 + t : t - nJ; };

  // prologue: DMA tiles KT(0)->buf0, KT(1)->buf1 (T >= 32 always)
  {
    const int ka = KT(0), kb = KT(1);
#pragma unroll
    for (int p2 = 0; p2 < 2; ++p2) {
      const int r = p2 * 32 + drow;
      gl2lds16(Kg + (size_t)(ka * 64 + r) * C3 + dsrc, Ks[0] + r * 64 + dslot);
      gl2lds16(Vg + (size_t)r * T_SEQ + ka * 64 + dsrc, Vs[0] + r * 64 + dslot);
    }
#pragma unroll
    for (int p2 = 0; p2 < 2; ++p2) {
      const int r = p2 * 32 + drow;
      gl2lds16(Kg + (size_t)(kb * 64 + r) * C3 + dsrc, Ks[1] + r * 64 + dslot);
      gl2lds16(Vg + (size_t)r * T_SEQ + kb * 64 + dsrc, Vs[1] + r * 64 + dslot);
    }
    asm volatile("s_waitcnt vmcnt(4)" ::: "memory");
    __builtin_amdgcn_s_barrier();
  }

  float l_i = 0.f;
  f32x4 o_acc[4];
#pragma unroll
  for (int dt = 0; dt < 4; ++dt) o_acc[dt] = (f32x4){0.f, 0.f, 0.f, 0.f};

  int ic = 0;  // buffer consumed (t % 3)
  int iw = 2;  // buffer filled  ((t+2) % 3)
  int t = 0;   // global task index

  auto body = [&](const bf16x8 (&qb)[2], int qtcur) __attribute__((always_inline)) {
    if (t + 2 < T) {
      const int k2 = KT(t + 2);
      unsigned short* Kd = Ks[iw];
      unsigned short* Vd = Vs[iw];
#pragma unroll
      for (int p2 = 0; p2 < 2; ++p2) {
        const int r = p2 * 32 + drow;
        gl2lds16(Kg + (size_t)(k2 * 64 + r) * C3 + dsrc, Kd + r * 64 + dslot);
        gl2lds16(Vg + (size_t)r * T_SEQ + k2 * 64 + dsrc, Vd + r * 64 + dslot);
      }
    }
    const unsigned short* Kc = Ks[ic];
    const unsigned short* Vc = Vs[ic];
    const int ktc = KT(t);

    // St = K @ Q^T
    f32x4 st[4];
#pragma unroll
    for (int mt = 0; mt < 4; ++mt) st[mt] = (f32x4){0.f, 0.f, 0.f, 0.f};
#pragma unroll
    for (int mt = 0; mt < 4; ++mt)
#pragma unroll
      for (int dh = 0; dh < 2; ++dh) {
        bf16x8 a = *(const bf16x8*)(
            Kc + (mt * 16 + lo) * 64 + (((dh * 4 + g) ^ lo7) * 8));
        st[mt] = __builtin_amdgcn_mfma_f32_16x16x32_bf16(a, qb[dh], st[mt], 0, 0, 0);
      }

    // causal mask on the diagonal tile of the current q-tile
    if (ktc == qtcur) {
      const int qloc = w * 16 + lo;
#pragma unroll
      for (int mt = 0; mt < 4; ++mt)
#pragma unroll
        for (int r = 0; r < 4; ++r)
          if (mt * 16 + g * 4 + r > qloc) st[mt][r] = -1e30f;
    }

    // no-max softmax: e = exp2(s * qscale)
    float lsum = 0.f;
    bf16x8 pt[2];
#pragma unroll
    for (int kh = 0; kh < 2; ++kh) {
#pragma unroll
      for (int jj = 0; jj < 4; ++jj) {
        float e0 = EXP2F(st[kh * 2][jj] * qscale);
        float e1 = EXP2F(st[kh * 2 + 1][jj] * qscale);
        lsum += e0 + e1;
        pt[kh][jj] = (short)f2bf_trunc(e0);
        pt[kh][4 + jj] = (short)f2bf_trunc(e1);
      }
    }
    l_i += lsum;

    // O^T += V^T @ P^T
#pragma unroll
    for (int dt = 0; dt < 4; ++dt)
#pragma unroll
      for (int kh = 0; kh < 2; ++kh) {
        bf16x8 av = *(const bf16x8*)(
            Vc + (dt * 16 + lo) * 64 + (((kh * 4 + g) ^ lo7) * 8));
        o_acc[dt] = __builtin_amdgcn_mfma_f32_16x16x32_bf16(av, pt[kh], o_acc[dt], 0, 0, 0);
      }

    // counted wait: tile t+1 (and anything older, incl. partial-flush
    // stores issued before this iter's DMAs) complete; tile t+2 in flight.
    if (t + 2 < T)
      asm volatile("s_waitcnt vmcnt(4)" ::: "memory");
    else
      asm volatile("s_waitcnt vmcnt(0)" ::: "memory");
    __builtin_amdgcn_s_barrier();

    ic = (ic == 2) ? 0 : ic + 1;
    iw = (iw == 2) ? 0 : iw + 1;
    ++t;
  };

  auto flush = [&](int slot, int qt) __attribute__((always_inline)) {
    float lred = l_i + __shfl_xor(l_i, 16);
    lred += __shfl_xor(lred, 32);
    float* PoS = Po + ((size_t)slot * NH + h) * (64 * 4096) + (size_t)qt * 4096;
#pragma unroll
    for (int dt = 0; dt < 4; ++dt)
      *(f32x4*)(PoS + (w * 16 + lo) * 64 + dt * 16 + g * 4) = o_acc[dt];
    if (g == 0)
      Pl[(((size_t)slot * NH + h) * 64 + qt) * 64 + w * 16 + lo] = lred;
    l_i = 0.f;
#pragma unroll
    for (int dt = 0; dt < 4; ++dt) o_acc[dt] = (f32x4){0.f, 0.f, 0.f, 0.f};
  };

  for (int u = 0; u < nJ; ++u) body(qbJ, j);
  if (nJ > 0) flush(s, j);     // s=0 -> slot0, s=1 -> slot1 (issued before
                               // the I-segment's first DMAs: vmcnt-safe)
  for (int u = 0; u < nI; ++u) body(qbI, i);
  if (nI > 0) flush(0, i);     // q-tiles 0..31 -> slot0
}

// ---------------------------------------------------------------------------
// combine: out = (O0 [+ O1]) / (l0 [+ l1]) -> bf16 attnb [4096][768]
// ---------------------------------------------------------------------------
__global__ __launch_bounds__(256) void combine_partials(
    const float* __restrict__ Po, const float* __restrict__ Pl,
    unsigned short* __restrict__ out) {
  const int bid = blockIdx.x;          // 768 = NH*64
  const int h = bid / 64, qt = bid % 64;
  const int tid = threadIdx.x;
  const int q = tid >> 2;
  const int c = (tid & 3) * 16;
  const bool two = (qt >= 33);
  const size_t sl = (size_t)h * 64 + qt;
  const float* P0 = Po + sl * 4096 + q * 64 + c;
  const float* P1 = P0 + PO_SLOT;
  float l = Pl[sl * 64 + q];
  if (two) l += Pl[PL_SLOT + sl * 64 + q];
  const float inv = 1.0f / l;
  unsigned short ob[16];
#pragma unroll
  for (int e = 0; e < 4; ++e) {
    f32x4 v = *(const f32x4*)(P0 + e * 4);
    if (two) {
      f32x4 v1 = *(const f32x4*)(P1 + e * 4);
      v += v1;
    }
#pragma unroll
    for (int r = 0; r < 4; ++r) ob[e * 4 + r] = f2bf(v[r] * inv);
  }
  unsigned short* o = out + (size_t)(qt * 64 + q) * C_DIM + h * 64 + c;
  *(uint4*)o = *(uint4*)ob;
  *(uint4*)(o + 8) = *(uint4*)(ob + 8);
}

// ---------------------------------------------------------------------------
extern "C" void kernel_launch(void* const* d_in, const int* in_sizes, int n_in,
                              void* d_out, int out_size, void* d_ws, size_t ws_size,
                              hipStream_t stream) {
  const float* x      = (const float*)d_in[0];
  const float* w_qkv  = (const float*)d_in[1];
  const float* b_qkv  = (const float*)d_in[2];
  const float* w_proj = (const float*)d_in[3];
  const float* b_proj = (const float*)d_in[4];
  float* out = (float*)d_out;

  unsigned short* xb     = (unsigned short*)d_ws;               // [4096,768]
  unsigned short* wqkvT  = xb + (size_t)T_SEQ * C_DIM;          // [2304,768]
  unsigned short* wprojT = wqkvT + (size_t)C3 * C_DIM;          // [768,768]
  unsigned short* qkv    = wprojT + (size_t)C_DIM * C_DIM;      // [4096,2304]
  unsigned short* vTp    = qkv + (size_t)T_SEQ * C3;            // [768,4096]
  unsigned short* attnb  = vTp + (size_t)C_DIM * T_SEQ;         // [4096,768]
  float* Po = (float*)(attnb + (size_t)T_SEQ * C_DIM);          // 2 slots fp32
  float* Pl = Po + 2 * PO_SLOT;                                 // 2 slots fp32

  prep_fused<<<NB_CONV + NB_TQKV + NB_TPROJ, 256, 0, stream>>>(
      x, w_qkv, w_proj, xb, wqkvT, wprojT);

  gemm_qkv<<<dim3(C3 / 128, T_SEQ / 128), 256, 0, stream>>>(
      xb, wqkvT, b_qkv, qkv, vTp, T_SEQ, C3, C_DIM);

  flash_attn_split14<<<T_SEQ / 64 * NH, 256, 0, stream>>>(qkv, vTp, Po, Pl);

  combine_partials<<<NH * 64, 256, 0, stream>>>(Po, Pl, attnb);

  gemm_bt_mfma<<<dim3(C_DIM / 128, T_SEQ / 128), 256, 0, stream>>>(
      attnb, wprojT, b_proj, out, T_SEQ, C_DIM, C_DIM);
}